// Round 1
// baseline (331.130 us; speedup 1.0000x reference)
//
#include <hip/hip_runtime.h>
#include <hip/hip_bf16.h>
#include <hip/hip_fp16.h>

#define NNODES 100000
#define NEDGES 1600000
#define NB     64
#define NG     16
#define POOL_SLOTS (NB * NG + NB)   // 1088: [64x16 pooled | 64 counts]

// CSR counting-sort parameters
#define BKT_SHIFT 7
#define NPB 128                               // nodes per bucket
#define NBKT ((NNODES + NPB - 1) / NPB)       // 782
#define BCAP 4096                             // per-bucket capacity (mean ~2046)
#define SCAT_BLOCKS 256
#define NL1_BLOCKS 2048
#define REC 128   // packed node record: [64B fp8 H | 16B fp32 AS | 48B pad] = 1 L2 line

typedef float vf2 __attribute__((ext_vector_type(2)));

__device__ __forceinline__ float leaky02(float v) {
    return v > 0.0f ? v : 0.2f * v;
}

// ---- fp8 (OCP e4m3, gfx950-native) helpers ----
__device__ __forceinline__ unsigned char cvt_fp8(float a) {
    int r = __builtin_amdgcn_cvt_pk_fp8_f32(a, a, 0, false);
    return (unsigned char)(r & 0xFF);
}

// load 4 consecutive fp8 as float4 (4-byte aligned) — 1 load + 2 pk-cvt
__device__ __forceinline__ float4 loadQ4(const unsigned char* p) {
    int u = *(const int*)p;
    vf2 lo = __builtin_amdgcn_cvt_pk_f32_fp8(u, false);
    vf2 hi = __builtin_amdgcn_cvt_pk_f32_fp8(u, true);
    return make_float4(lo.x, lo.y, hi.x, hi.y);
}

__device__ __forceinline__ void storeH4(__half* p, float4 v) {
    __half2 a = __floats2half2_rn(v.x, v.y);
    __half2 b = __floats2half2_rn(v.z, v.w);
    uint2 raw;
    raw.x = *reinterpret_cast<unsigned*>(&a);
    raw.y = *reinterpret_cast<unsigned*>(&b);
    *(uint2*)p = raw;
}

// ---------------------------------------------------------------------------
// node_linear device body: wave-per-node, lane = output channel (h*16+c).
// Writes the packed record: H fp8 at row[0..63], AS fp32 at row[64..79].
// AD stays a separate [n,4] array (dst-side only, never gathered per-edge).
// ---------------------------------------------------------------------------
template <int FIN>
__device__ __forceinline__ void nl_body_f32(const float* __restrict__ X,
                                            const float* __restrict__ W,
                                            const float* __restrict__ a_s,
                                            const float* __restrict__ a_d,
                                            unsigned char* __restrict__ Hrec,
                                            float* __restrict__ AD, int n,
                                            int wave0, int nwaves, int lane) {
    int head = lane >> 4;
    float w[FIN];
#pragma unroll
    for (int k = 0; k < FIN; ++k) w[k] = W[k * 64 + lane];
    float asl = a_s[lane], adl = a_d[lane];

    for (int i = wave0; i < n; i += nwaves) {
        const float* __restrict__ xr = X + (size_t)i * FIN;  // uniform address
        float acc = 0.0f;
#pragma unroll
        for (int k = 0; k < FIN; ++k) acc += xr[k] * w[k];
        unsigned char* row = Hrec + (size_t)i * REC;
        row[lane] = cvt_fp8(acc);
        float s1 = acc * asl, s2 = acc * adl;
#pragma unroll
        for (int off = 1; off < 16; off <<= 1) {
            s1 += __shfl_xor(s1, off);
            s2 += __shfl_xor(s2, off);
        }
        if ((lane & 15) == 0) {
            ((float*)(row + 64))[head] = s1;
            AD[(size_t)i * 4 + head] = s2;
        }
    }
}

// fp16-input variant (layer 2): rows read as wave-uniform u32 loads.
template <int FIN>
__global__ void node_linear3h(const unsigned* __restrict__ X,  // [n, FIN/2] u32
                              const float* __restrict__ W,
                              const float* __restrict__ a_s,
                              const float* __restrict__ a_d,
                              unsigned char* __restrict__ Hrec,
                              float* __restrict__ AD, int n) {
    int lane = threadIdx.x & 63;
    int head = lane >> 4;
    int wave = __builtin_amdgcn_readfirstlane(
        (int)((blockIdx.x * blockDim.x + threadIdx.x) >> 6));
    int nwaves = (gridDim.x * blockDim.x) >> 6;

    float w[FIN];
#pragma unroll
    for (int k = 0; k < FIN; ++k) w[k] = W[k * 64 + lane];
    float asl = a_s[lane], adl = a_d[lane];

    for (int i = wave; i < n; i += nwaves) {
        const unsigned* __restrict__ xr = X + (size_t)i * (FIN / 2);  // uniform
        float acc = 0.0f;
#pragma unroll
        for (int k = 0; k < FIN / 2; ++k) {
            unsigned u = xr[k];
            __half2 hh = *reinterpret_cast<const __half2*>(&u);
            float2 f = __half22float2(hh);
            acc += f.x * w[2 * k] + f.y * w[2 * k + 1];
        }
        unsigned char* row = Hrec + (size_t)i * REC;
        row[lane] = cvt_fp8(acc);
        float s1 = acc * asl, s2 = acc * adl;
#pragma unroll
        for (int off = 1; off < 16; off <<= 1) {
            s1 += __shfl_xor(s1, off);
            s2 += __shfl_xor(s2, off);
        }
        if ((lane & 15) == 0) {
            ((float*)(row + 64))[head] = s1;
            AD[(size_t)i * 4 + head] = s2;
        }
    }
}

// ---------------------------------------------------------------------------
// FUSED: bucket_scatter (blocks [0,SCAT_BLOCKS)) + layer-1 node_linear.
// ---------------------------------------------------------------------------
__global__ void scatter_nl1(const int* __restrict__ src,
                            const int* __restrict__ dst,
                            int* __restrict__ bucketCnt,
                            unsigned int* __restrict__ pairs, int ne,
                            const float* __restrict__ X,
                            const float* __restrict__ W,
                            const float* __restrict__ a_s,
                            const float* __restrict__ a_d,
                            unsigned char* __restrict__ Hrec,
                            float* __restrict__ AD, int n) {
    __shared__ int hist[NBKT];
    __shared__ int base[NBKT];
    int tid = threadIdx.x;

    if (blockIdx.x >= SCAT_BLOCKS) {
        // ---- node_linear part ----
        int lane = tid & 63;
        int wave = __builtin_amdgcn_readfirstlane(
            (int)(((blockIdx.x - SCAT_BLOCKS) * blockDim.x + tid) >> 6));
        int nwaves = (NL1_BLOCKS * 256) >> 6;
        nl_body_f32<16>(X, W, a_s, a_d, Hrec, AD, n, wave, nwaves, lane);
        return;
    }

    // ---- scatter part ----
    for (int i = tid; i < NBKT; i += 256) hist[i] = 0;
    __syncthreads();

    int chunk = (ne + SCAT_BLOCKS - 1) / SCAT_BLOCKS;
    int beg = blockIdx.x * chunk;
    int end = min(beg + chunk, ne);

    // phase 1: histogram, 4 coalesced loads in flight
    for (int e0 = beg; e0 < end; e0 += 1024) {
        int d[4];
#pragma unroll
        for (int q = 0; q < 4; ++q) {
            int e = e0 + q * 256 + tid;
            d[q] = (e < end) ? dst[e] : -1;
        }
#pragma unroll
        for (int q = 0; q < 4; ++q)
            if (d[q] >= 0) atomicAdd(&hist[d[q] >> BKT_SHIFT], 1);
    }
    __syncthreads();

    for (int i = tid; i < NBKT; i += 256) {
        int h = hist[i];
        base[i] = h ? atomicAdd(&bucketCnt[i], h) : 0;  // reserve range
        hist[i] = 0;                                    // reuse as cursor
    }
    __syncthreads();

    // phase 3: scatter, 4 edges batched
    for (int e0 = beg; e0 < end; e0 += 1024) {
        int d[4], s[4];
#pragma unroll
        for (int q = 0; q < 4; ++q) {
            int e = e0 + q * 256 + tid;
            d[q] = (e < end) ? dst[e] : -1;
            s[q] = (e < end) ? src[e] : 0;
        }
        int r[4], bkt[4];
#pragma unroll
        for (int q = 0; q < 4; ++q) {
            if (d[q] >= 0) {
                bkt[q] = d[q] >> BKT_SHIFT;
                r[q] = base[bkt[q]] + atomicAdd(&hist[bkt[q]], 1);
            }
        }
#pragma unroll
        for (int q = 0; q < 4; ++q) {
            if (d[q] >= 0 && r[q] < BCAP)
                pairs[(size_t)bkt[q] * BCAP + r[q]] =
                    (unsigned)s[q] | ((unsigned)(d[q] & (NPB - 1)) << 20);
        }
    }
}

// ---------------------------------------------------------------------------
// bucket_sort with inline offset computation
// ---------------------------------------------------------------------------
__global__ void bucket_sort(const unsigned int* __restrict__ pairs,
                            const int* __restrict__ bucketCnt,
                            int* __restrict__ srcs,
                            int* __restrict__ indptr, int n) {
    __shared__ int hist[NPB];
    __shared__ int offl[NPB];
    __shared__ int cur[NPB];
    __shared__ int red[256];
    __shared__ int lsrc[BCAP];
    int bkt = blockIdx.x;
    int t = threadIdx.x;
    int cnt = min(bucketCnt[bkt], BCAP);

    int partial = 0;
    for (int j = t; j < bkt; j += 256) partial += min(bucketCnt[j], BCAP);
    red[t] = partial;
    if (t < NPB) hist[t] = 0;
    __syncthreads();
    for (int s = 128; s > 0; s >>= 1) {
        if (t < s) red[t] += red[t + s];
        __syncthreads();
    }
    int boff = red[0];
    if (bkt == NBKT - 1 && t == 0) indptr[n] = boff + cnt;

    const unsigned int* __restrict__ p = pairs + (size_t)bkt * BCAP;
    unsigned int v[BCAP / 256];
#pragma unroll
    for (int i = 0; i < BCAP / 256; ++i) {
        int e = i * 256 + t;
        v[i] = 0u;
        if (e < cnt) {
            v[i] = p[e];
            atomicAdd(&hist[v[i] >> 20], 1);
        }
    }
    __syncthreads();
    if (t < NPB) offl[t] = hist[t];
    __syncthreads();
    for (int off = 1; off < NPB; off <<= 1) {
        int x = 0;
        if (t < NPB && t >= off) x = offl[t - off];
        __syncthreads();
        if (t < NPB && t >= off) offl[t] += x;
        __syncthreads();
    }
    if (t < NPB) {
        int ex = offl[t] - hist[t];   // exclusive
        cur[t] = ex;
        int node = bkt * NPB + t;
        if (node < n) indptr[node] = boff + ex;
    }
    __syncthreads();
#pragma unroll
    for (int i = 0; i < BCAP / 256; ++i) {
        int e = i * 256 + t;
        if (e < cnt) {
            int r = atomicAdd(&cur[v[i] >> 20], 1);
            lsrc[r] = (int)(v[i] & 0xFFFFFu);
        }
    }
    __syncthreads();
    for (int e = t; e < cnt; e += 256) srcs[boff + e] = lsrc[e];
}

// ---------------------------------------------------------------------------
// Pull-mode GAT aggregation core: 4 dst nodes/wave, 16-lane group per node.
// Packed record => H dword + AS dword from the SAME 128B line per edge.
// Returns per-lane normalized float4 (channels 4*sl..4*sl+3, concat layout).
// ---------------------------------------------------------------------------
__device__ __forceinline__ float4 gat_agg_core(
    const unsigned char* __restrict__ Hrec, const float* __restrict__ AD,
    const int* __restrict__ indptr, const int* __restrict__ srcs,
    int d, int grp, int sl, int head) {
    const unsigned char* __restrict__ rowD = Hrec + (size_t)d * REC;
    float ad  = AD[(size_t)d * 4 + head];
    float asd = *(const float*)(rowD + 64 + 4 * head);
    float t0 = asd + ad;                       // self-loop
    float wself = __expf(leaky02(t0));
    float den = wself;
    float4 h4s = loadQ4(rowD + sl * 4);
    float4 acc = make_float4(wself * h4s.x, wself * h4s.y,
                             wself * h4s.z, wself * h4s.w);

    int beg = indptr[d], end = indptr[d + 1];
    for (int e0 = beg; e0 < end; e0 += 16) {
        int cnt = min(16, end - e0);
        int myS = (sl < cnt) ? srcs[e0 + sl] : 0;  // coalesced per group
        int j = 0;
        for (; j + 4 <= cnt; j += 4) {             // 4 line-gathers in flight
            const unsigned char* r[4];
            float a[4]; float4 h4[4];
#pragma unroll
            for (int q = 0; q < 4; ++q) {
                int s = __shfl(myS, (grp << 4) + j + q);
                r[q] = Hrec + (size_t)s * REC;
            }
#pragma unroll
            for (int q = 0; q < 4; ++q)
                a[q] = *(const float*)(r[q] + 64 + 4 * head);
#pragma unroll
            for (int q = 0; q < 4; ++q) h4[q] = loadQ4(r[q] + sl * 4);
#pragma unroll
            for (int q = 0; q < 4; ++q) {
                float t = a[q] + ad;
                float w = __expf(leaky02(t));
                den += w;
                acc.x += w * h4[q].x; acc.y += w * h4[q].y;
                acc.z += w * h4[q].z; acc.w += w * h4[q].w;
            }
        }
        for (; j < cnt; ++j) {                     // tail
            int s = __shfl(myS, (grp << 4) + j);
            const unsigned char* rr = Hrec + (size_t)s * REC;
            float t = *(const float*)(rr + 64 + 4 * head) + ad;
            float w = __expf(leaky02(t));
            float4 h4 = loadQ4(rr + sl * 4);
            den += w;
            acc.x += w * h4.x; acc.y += w * h4.y;
            acc.z += w * h4.z; acc.w += w * h4.w;
        }
    }
    float inv = 1.0f / (den + 1e-16f);
    return make_float4(acc.x * inv, acc.y * inv, acc.z * inv, acc.w * inv);
}

// layer 1: concat 64ch + bias + ELU -> fp16 [n,64]
__global__ void gat_pull_l1(const unsigned char* __restrict__ Hrec,
                            const float* __restrict__ AD,
                            const int* __restrict__ indptr,
                            const int* __restrict__ srcs,
                            const float* __restrict__ bias,
                            __half* __restrict__ out, int n) {
    int lane = threadIdx.x & 63;
    int grp = lane >> 4, sl = lane & 15, head = sl >> 2;
    int wave = (blockIdx.x * blockDim.x + threadIdx.x) >> 6;
    int nwaves = (gridDim.x * blockDim.x) >> 6;
    for (int d0 = wave * 4; d0 < n; d0 += nwaves * 4) {
        int d = d0 + grp;
        if (d < n) {
            float4 v = gat_agg_core(Hrec, AD, indptr, srcs, d, grp, sl, head);
            float4 b4 = *(const float4*)(bias + sl * 4);
            v.x += b4.x; v.y += b4.y; v.z += b4.z; v.w += b4.w;
            v.x = v.x > 0.f ? v.x : __expf(v.x) - 1.f;
            v.y = v.y > 0.f ? v.y : __expf(v.y) - 1.f;
            v.z = v.z > 0.f ? v.z : __expf(v.z) - 1.f;
            v.w = v.w > 0.f ? v.w : __expf(v.w) - 1.f;
            storeH4(out + (size_t)d * 64 + sl * 4, v);
        }
    }
}

// layer 2: head-mean + b2 + ELU, then FUSED layer-3 node_linear (16->64):
// writes the layer-3 packed record (Hout) + AD in place.
__global__ void gat_pull_l2(const unsigned char* __restrict__ Hrec,
                            float* __restrict__ AD,
                            const int* __restrict__ indptr,
                            const int* __restrict__ srcs,
                            const float* __restrict__ bias,   // b2 [16]
                            const float* __restrict__ W3,     // [16][64]
                            const float* __restrict__ a3s,    // [4][16]
                            const float* __restrict__ a3d,    // [4][16]
                            unsigned char* __restrict__ Hout, int n) {
    __shared__ float w3s[16 * 64];
    for (int i = threadIdx.x; i < 16 * 64; i += 256) w3s[i] = W3[i];
    __syncthreads();

    int lane = threadIdx.x & 63;
    int grp = lane >> 4, sl = lane & 15, head = sl >> 2;
    int wave = (blockIdx.x * blockDim.x + threadIdx.x) >> 6;
    int nwaves = (gridDim.x * blockDim.x) >> 6;
    // lane's layer-3 output channels are 4*sl..4*sl+3 => head sl>>2, c-quad sl&3
    float4 as4 = *(const float4*)(a3s + head * 16 + (sl & 3) * 4);
    float4 ad4 = *(const float4*)(a3d + head * 16 + (sl & 3) * 4);
    float4 b4  = *(const float4*)(bias + (sl & 3) * 4);

    for (int d0 = wave * 4; d0 < n; d0 += nwaves * 4) {
        int d = d0 + grp;
        if (d < n) {
            float4 v = gat_agg_core(Hrec, AD, indptr, srcs, d, grp, sl, head);
            // head-mean fold: lane sl ends with quad (sl&3) summed over heads
#pragma unroll
            for (int off = 4; off <= 8; off <<= 1) {
                v.x += __shfl_xor(v.x, off);
                v.y += __shfl_xor(v.y, off);
                v.z += __shfl_xor(v.z, off);
                v.w += __shfl_xor(v.w, off);
            }
            v.x = 0.25f * v.x + b4.x; v.y = 0.25f * v.y + b4.y;
            v.z = 0.25f * v.z + b4.z; v.w = 0.25f * v.w + b4.w;
            v.x = v.x > 0.f ? v.x : __expf(v.x) - 1.f;
            v.y = v.y > 0.f ? v.y : __expf(v.y) - 1.f;
            v.z = v.z > 0.f ? v.z : __expf(v.z) - 1.f;
            v.w = v.w > 0.f ? v.w : __expf(v.w) - 1.f;

            // broadcast the 16 layer-3 inputs (quad q lives in group lane q)
            float xin[16];
#pragma unroll
            for (int q = 0; q < 4; ++q) {
                int srcl = (grp << 4) + q;
                xin[4 * q + 0] = __shfl(v.x, srcl);
                xin[4 * q + 1] = __shfl(v.y, srcl);
                xin[4 * q + 2] = __shfl(v.z, srcl);
                xin[4 * q + 3] = __shfl(v.w, srcl);
            }
            // 16->64 matmul: lane computes channels 4*sl..4*sl+3
            float4 o = make_float4(0.f, 0.f, 0.f, 0.f);
#pragma unroll
            for (int k = 0; k < 16; ++k) {
                float4 wr = *(const float4*)&w3s[k * 64 + 4 * sl];
                o.x += xin[k] * wr.x; o.y += xin[k] * wr.y;
                o.z += xin[k] * wr.z; o.w += xin[k] * wr.w;
            }
            unsigned char* rowO = Hout + (size_t)d * REC;
            int pk = __builtin_amdgcn_cvt_pk_fp8_f32(o.x, o.y, 0, false);
            pk = __builtin_amdgcn_cvt_pk_fp8_f32(o.z, o.w, pk, true);
            *(int*)(rowO + 4 * sl) = pk;
            float s1 = o.x * as4.x + o.y * as4.y + o.z * as4.z + o.w * as4.w;
            float s2 = o.x * ad4.x + o.y * ad4.y + o.z * ad4.z + o.w * ad4.w;
            s1 += __shfl_xor(s1, 1); s1 += __shfl_xor(s1, 2);
            s2 += __shfl_xor(s2, 1); s2 += __shfl_xor(s2, 2);
            if ((sl & 3) == 0) {
                ((float*)(rowO + 64))[head] = s1;
                AD[(size_t)d * 4 + head] = s2;   // read-before-write within group
            }
        }
    }
}

// layer 3: head-mean + b3 (no act), FUSED mean-pool accumulation into PC.
__global__ void gat_pull_l3(const unsigned char* __restrict__ Hrec,
                            const float* __restrict__ AD,
                            const int* __restrict__ indptr,
                            const int* __restrict__ srcs,
                            const float* __restrict__ bias,   // b3 [16]
                            const int* __restrict__ batch,
                            float* __restrict__ PC, int n) {
    __shared__ float lp[POOL_SLOTS];
    for (int i = threadIdx.x; i < POOL_SLOTS; i += 256) lp[i] = 0.f;
    __syncthreads();

    int lane = threadIdx.x & 63;
    int grp = lane >> 4, sl = lane & 15, head = sl >> 2;
    int wave = (blockIdx.x * blockDim.x + threadIdx.x) >> 6;
    int nwaves = (gridDim.x * blockDim.x) >> 6;
    float4 b4 = *(const float4*)(bias + (sl & 3) * 4);

    for (int d0 = wave * 4; d0 < n; d0 += nwaves * 4) {
        int d = d0 + grp;
        if (d < n) {
            float4 v = gat_agg_core(Hrec, AD, indptr, srcs, d, grp, sl, head);
#pragma unroll
            for (int off = 4; off <= 8; off <<= 1) {
                v.x += __shfl_xor(v.x, off);
                v.y += __shfl_xor(v.y, off);
                v.z += __shfl_xor(v.z, off);
                v.w += __shfl_xor(v.w, off);
            }
            v.x = 0.25f * v.x + b4.x; v.y = 0.25f * v.y + b4.y;
            v.z = 0.25f * v.z + b4.z; v.w = 0.25f * v.w + b4.w;
            if (sl < 4) {                 // lanes 0..3 hold quads 0..3
                int b = batch[d];
                atomicAdd(&lp[b * 16 + sl * 4 + 0], v.x);
                atomicAdd(&lp[b * 16 + sl * 4 + 1], v.y);
                atomicAdd(&lp[b * 16 + sl * 4 + 2], v.z);
                atomicAdd(&lp[b * 16 + sl * 4 + 3], v.w);
                if (sl == 0) atomicAdd(&lp[NB * NG + b], 1.0f);
            }
        }
    }
    __syncthreads();
    // block covers 16 consecutive nodes -> ~1-2 graphs touched; sparse flush
    for (int i = threadIdx.x; i < POOL_SLOTS; i += 256) {
        float s = lp[i];
        if (s != 0.f) atomicAdd(&PC[i], s);
    }
}

// final MLP head, one thread per graph
__global__ void mlp_head(const float* __restrict__ pooled_counts,
                         const float* __restrict__ stats,
                         const float* __restrict__ fw1, const float* __restrict__ fb1,
                         const float* __restrict__ fw2, const float* __restrict__ fb2,
                         const float* __restrict__ fw3, const float* __restrict__ fb3,
                         float* __restrict__ out) {
    int g = threadIdx.x;
    if (g >= NB) return;
    const float* pooled = pooled_counts;
    const float* counts = pooled_counts + NB * NG;
    float z[32];
    float inv = 1.0f / fmaxf(counts[g], 1.0f);
#pragma unroll
    for (int c = 0; c < 16; ++c) z[c] = pooled[g * 16 + c] * inv;
#pragma unroll
    for (int c = 0; c < 16; ++c) z[16 + c] = stats[g * 16 + c];

    float z1[32];
#pragma unroll
    for (int j = 0; j < 32; ++j) {
        float acc = fb1[j];
        for (int k = 0; k < 32; ++k) acc += z[k] * fw1[k * 32 + j];
        z1[j] = fmaxf(acc, 0.0f);
    }
    float z2[16];
#pragma unroll
    for (int j = 0; j < 16; ++j) {
        float acc = fb2[j];
        for (int k = 0; k < 32; ++k) acc += z1[k] * fw2[k * 16 + j];
        z2[j] = fmaxf(acc, 0.0f);
    }
    float acc = fb3[0];
#pragma unroll
    for (int k = 0; k < 16; ++k) acc += z2[k] * fw3[k];
    out[g] = acc;
}

extern "C" void kernel_launch(void* const* d_in, const int* in_sizes, int n_in,
                              void* d_out, int out_size, void* d_ws, size_t ws_size,
                              hipStream_t stream) {
    const float* x    = (const float*)d_in[0];
    const float* stats= (const float*)d_in[1];
    const float* W1   = (const float*)d_in[2];
    const float* a1s  = (const float*)d_in[3];
    const float* a1d  = (const float*)d_in[4];
    const float* b1   = (const float*)d_in[5];
    const float* W2   = (const float*)d_in[6];
    const float* a2s  = (const float*)d_in[7];
    const float* a2d  = (const float*)d_in[8];
    const float* b2   = (const float*)d_in[9];
    const float* W3   = (const float*)d_in[10];
    const float* a3s  = (const float*)d_in[11];
    const float* a3d  = (const float*)d_in[12];
    const float* b3   = (const float*)d_in[13];
    const float* fw1  = (const float*)d_in[14];
    const float* fb1  = (const float*)d_in[15];
    const float* fw2  = (const float*)d_in[16];
    const float* fb2  = (const float*)d_in[17];
    const float* fw3  = (const float*)d_in[18];
    const float* fb3  = (const float*)d_in[19];
    const int* ei     = (const int*)d_in[20];
    const int* batch  = (const int*)d_in[21];

    const int n = NNODES, ne = NEDGES;
    const int* srcI = ei;
    const int* dstI = ei + ne;

    // ---- workspace layout ----
    unsigned char* HqA = (unsigned char*)d_ws;            // [n,128] 12.8MB
    unsigned char* HqB = HqA + (size_t)n * REC;           // [n,128] 12.8MB
    float* AD   = (float*)(HqB + (size_t)n * REC);        // [n,4]   1.6MB
    float* PC   = AD + (size_t)n * 4;                     // [1088]
    int* bucketCnt = (int*)(PC + POOL_SLOTS);             // [NBKT]
    int* indptr    = bucketCnt + NBKT;                    // [n+1]
    int* srcs      = indptr + (n + 1);                    // [ne]
    size_t off = (size_t)((char*)(srcs + ne) - (char*)d_ws);
    off = (off + 255) & ~(size_t)255;
    unsigned int* pairs = (unsigned int*)((char*)d_ws + off); // 12.82MB
    __half* B16 = (__half*)pairs;   // layer-1 out fp16 [n,64]; pairs dead by then

    const int TB = 256;
    const int nlBlocks   = 2048;
    const int pullBlocks = (n + 15) / 16;   // 4 waves/blk × 4 nodes/wave

    // PC and bucketCnt are contiguous: one memset covers both
    hipMemsetAsync(PC, 0, (POOL_SLOTS + NBKT) * sizeof(int), stream);

    // ---- fused: CSR bucket scatter + layer-1 node_linear ----
    scatter_nl1<<<SCAT_BLOCKS + NL1_BLOCKS, TB, 0, stream>>>(
        srcI, dstI, bucketCnt, pairs, ne,
        x, W1, a1s, a1d, HqA, AD, n);
    bucket_sort<<<NBKT, TB, 0, stream>>>(pairs, bucketCnt, srcs, indptr, n);

    // ---- layer 1 aggregate: 16 -> 4x16 concat, elu (fp16 out) ----
    gat_pull_l1<<<pullBlocks, TB, 0, stream>>>(HqA, AD, indptr, srcs, b1, B16, n);

    // ---- layer 2 linear: 64 (fp16 in) -> packed record ----
    node_linear3h<64><<<nlBlocks, TB, 0, stream>>>((const unsigned*)B16, W2,
                                                   a2s, a2d, HqA, AD, n);
    // ---- layer 2 aggregate + FUSED layer-3 linear ----
    gat_pull_l2<<<pullBlocks, TB, 0, stream>>>(HqA, AD, indptr, srcs, b2,
                                               W3, a3s, a3d, HqB, n);
    // ---- layer 3 aggregate + FUSED mean-pool ----
    gat_pull_l3<<<pullBlocks, TB, 0, stream>>>(HqB, AD, indptr, srcs, b3,
                                               batch, PC, n);

    // ---- MLP head ----
    mlp_head<<<1, 64, 0, stream>>>(PC, stats, fw1, fb1, fw2, fb2, fw3, fb3,
                                   (float*)d_out);
}